// Round 12
// baseline (715.731 us; speedup 1.0000x reference)
//
#include <hip/hip_runtime.h>
#include <math.h>

#define HIDF 256
#define FPDIM 1034
#define MPAD 50048     // 50000 rounded up to 128
#define FCM 2048       // fc1 M pad (B=2000)
#define FCK 1344       // fc1 K pad (1290 -> 21*64)
#define FCSLICES 3
#define FCKSLICE 448   // 7 K-steps per slice

typedef _Float16 f16x8 __attribute__((ext_vector_type(8)));
typedef _Float16 f16x4 __attribute__((ext_vector_type(4)));
typedef float f32x4 __attribute__((ext_vector_type(4)));

__device__ __forceinline__ float relu_f(float v) { return fmaxf(v, 0.f); }

// ---------------- x fp32 -> fp16 [MPAD][256], zero pad ----------------
__global__ __launch_bounds__(256) void convxh_k(
    const float* __restrict__ x, _Float16* __restrict__ xh, int n)
{
    int i = blockIdx.x * 256 + threadIdx.x;
    int row = i >> 6;
    if (row >= MPAD) return;
    f16x4 o;
    if (row < n) {
        float4 v = ((const float4*)x)[i];
        o[0] = (_Float16)v.x; o[1] = (_Float16)v.y;
        o[2] = (_Float16)v.z; o[3] = (_Float16)v.w;
    } else {
        o[0] = o[1] = o[2] = o[3] = (_Float16)0.f;
    }
    ((f16x4*)xh)[i] = o;
}

// ---- merged weight split: y<9 square weights -> whi/wlo; y==9 fc1w -----------
__global__ __launch_bounds__(256) void convw_all_k(
    const float* __restrict__ lin_w, const float* __restrict__ upd_w,
    const float* __restrict__ g1w, const float* __restrict__ fc1w,
    _Float16* __restrict__ whi, _Float16* __restrict__ wlo,
    _Float16* __restrict__ fwhi, _Float16* __restrict__ fwlo)
{
    int m = blockIdx.y;
    int i = blockIdx.x * 256 + threadIdx.x;
    if (m < 9) {
        if (i >= 65536) return;
        const float* src = (m < 4) ? (lin_w + (size_t)m * 257 * 256)
                         : (m < 8) ? (upd_w + (size_t)(m - 4) * 65536)
                                   : g1w;
        int nn = i >> 8, kk = i & 255;
        float v = src[kk * 256 + nn];
        _Float16 h = (_Float16)v;
        _Float16 l = (_Float16)(v - (float)h);
        whi[(size_t)m * 65536 + i] = h;
        wlo[(size_t)m * 65536 + i] = l;
    } else {
        if (i >= HIDF * FCK) return;
        int nn = i / FCK, kk = i - nn * FCK;
        float v = (kk < HIDF + FPDIM) ? fc1w[(size_t)kk * HIDF + nn] : 0.f;
        _Float16 h = (_Float16)v;
        _Float16 l = (_Float16)(v - (float)h);
        fwhi[i] = h;
        fwlo[i] = l;
    }
}

// ------- fc1 input: [pooled | fp] -> split fp16 hi/lo [FCM][FCK] --------------
__global__ __launch_bounds__(256) void convfc1a_k(
    const float* __restrict__ pooled, const float* __restrict__ fp,
    _Float16* __restrict__ ahi, _Float16* __restrict__ alo, int B)
{
    int i = blockIdx.x * 256 + threadIdx.x;
    if (i >= FCM * FCK) return;
    int row = i / FCK, col = i - row * FCK;
    float v = 0.f;
    if (row < B) {
        if (col < HIDF) v = pooled[(size_t)row * HIDF + col];
        else if (col < HIDF + FPDIM) v = fp[(size_t)row * FPDIM + (col - HIDF)];
    }
    _Float16 h = (_Float16)v;
    _Float16 l = (_Float16)(v - (float)h);
    ahi[i] = h;
    alo[i] = l;
}

// ---------------- fp16 MFMA GEMM: C = act(A @ W^T + bias), fp16 out -----------
// BM=BN=128, BK=64, 4 waves (2x2 of 64x64), mfma_f32_16x16x32_f16.
// TERMS=2: acc = A*Whi + A*Wlo (~22-bit weights). TERMS=1: pure fp16 weights.
template <int ACT, int TERMS>
__global__ __launch_bounds__(256) void gemm_f16(
    const _Float16* __restrict__ A, const _Float16* __restrict__ Whi,
    const _Float16* __restrict__ Wlo, const float* __restrict__ bias,
    _Float16* __restrict__ C, int M, int N, int K)
{
    __shared__ _Float16 As[128 * 64];
    __shared__ _Float16 Bh[128 * 64];
    __shared__ _Float16 Bl[(TERMS == 2) ? 128 * 64 : 64];
    const int tid = threadIdx.x;
    const int wave = tid >> 6, lane = tid & 63;
    const int m0 = blockIdx.y * 128, n0 = blockIdx.x * 128;
    const int wr = wave >> 1, wc = wave & 1;

    f32x4 acc[4][4];
#pragma unroll
    for (int i = 0; i < 4; ++i)
#pragma unroll
        for (int j = 0; j < 4; ++j) acc[i][j] = (f32x4){0.f, 0.f, 0.f, 0.f};

    const int lrow = lane >> 3;
    const int lcol8 = (lane & 7) * 8;

    for (int k0 = 0; k0 < K; k0 += 64) {
#pragma unroll
        for (int i = 0; i < 4; ++i) {
            int iss = wave * 4 + i;
            int row = 8 * iss + lrow;
            const _Float16* ga = A   + (size_t)(m0 + row) * K + k0 + lcol8;
            const _Float16* gh = Whi + (size_t)(n0 + row) * K + k0 + lcol8;
            __builtin_amdgcn_global_load_lds(
                (const __attribute__((address_space(1))) void*)ga,
                (__attribute__((address_space(3))) void*)(As + iss * 512), 16, 0, 0);
            __builtin_amdgcn_global_load_lds(
                (const __attribute__((address_space(1))) void*)gh,
                (__attribute__((address_space(3))) void*)(Bh + iss * 512), 16, 0, 0);
            if constexpr (TERMS == 2) {
                const _Float16* gl = Wlo + (size_t)(n0 + row) * K + k0 + lcol8;
                __builtin_amdgcn_global_load_lds(
                    (const __attribute__((address_space(1))) void*)gl,
                    (__attribute__((address_space(3))) void*)(Bl + iss * 512), 16, 0, 0);
            }
        }
        __syncthreads();
#pragma unroll
        for (int kk = 0; kk < 2; ++kk) {
            const int kb = kk * 32 + (lane >> 4) * 8;
            f16x8 af[4], bh[4], bl[4];
#pragma unroll
            for (int mi = 0; mi < 4; ++mi)
                af[mi] = *(const f16x8*)&As[(wr * 64 + mi * 16 + (lane & 15)) * 64 + kb];
#pragma unroll
            for (int ni = 0; ni < 4; ++ni) {
                int r = (wc * 64 + ni * 16 + (lane & 15)) * 64 + kb;
                bh[ni] = *(const f16x8*)&Bh[r];
                if constexpr (TERMS == 2) bl[ni] = *(const f16x8*)&Bl[r];
            }
#pragma unroll
            for (int mi = 0; mi < 4; ++mi)
#pragma unroll
                for (int ni = 0; ni < 4; ++ni) {
                    acc[mi][ni] = __builtin_amdgcn_mfma_f32_16x16x32_f16(
                        af[mi], bh[ni], acc[mi][ni], 0, 0, 0);
                    if constexpr (TERMS == 2)
                        acc[mi][ni] = __builtin_amdgcn_mfma_f32_16x16x32_f16(
                            af[mi], bl[ni], acc[mi][ni], 0, 0, 0);
                }
        }
        __syncthreads();
    }

    const int crow0 = m0 + wr * 64 + (lane >> 4) * 4;
    const int ccol0 = n0 + wc * 64 + (lane & 15);
#pragma unroll
    for (int mi = 0; mi < 4; ++mi) {
#pragma unroll
        for (int ni = 0; ni < 4; ++ni) {
            int col = ccol0 + ni * 16;
            float bv = bias ? bias[col] : 0.f;
#pragma unroll
            for (int r = 0; r < 4; ++r) {
                int row = crow0 + mi * 16 + r;
                float v = acc[mi][ni][r] + bv;
                if (ACT == 1) v = relu_f(v);
                C[(size_t)row * N + col] = (_Float16)v;
            }
        }
    }
}

// ------- fused gate GEMM (1-term): gacc[row] += dot(tanh(A@g1w^T+g1b), g2w) ---
__global__ __launch_bounds__(256) void gemm_gate(
    const _Float16* __restrict__ A, const _Float16* __restrict__ Whi,
    const float* __restrict__ g1b, const float* __restrict__ g2w,
    float* __restrict__ gacc, int M, int N, int K)
{
    __shared__ _Float16 As[128 * 64];
    __shared__ _Float16 Bh[128 * 64];
    const int tid = threadIdx.x;
    const int wave = tid >> 6, lane = tid & 63;
    const int m0 = blockIdx.y * 128, n0 = blockIdx.x * 128;
    const int wr = wave >> 1, wc = wave & 1;

    f32x4 acc[4][4];
#pragma unroll
    for (int i = 0; i < 4; ++i)
#pragma unroll
        for (int j = 0; j < 4; ++j) acc[i][j] = (f32x4){0.f, 0.f, 0.f, 0.f};

    const int lrow = lane >> 3;
    const int lcol8 = (lane & 7) * 8;

    for (int k0 = 0; k0 < K; k0 += 64) {
#pragma unroll
        for (int i = 0; i < 4; ++i) {
            int iss = wave * 4 + i;
            int row = 8 * iss + lrow;
            const _Float16* ga = A   + (size_t)(m0 + row) * K + k0 + lcol8;
            const _Float16* gh = Whi + (size_t)(n0 + row) * K + k0 + lcol8;
            __builtin_amdgcn_global_load_lds(
                (const __attribute__((address_space(1))) void*)ga,
                (__attribute__((address_space(3))) void*)(As + iss * 512), 16, 0, 0);
            __builtin_amdgcn_global_load_lds(
                (const __attribute__((address_space(1))) void*)gh,
                (__attribute__((address_space(3))) void*)(Bh + iss * 512), 16, 0, 0);
        }
        __syncthreads();
#pragma unroll
        for (int kk = 0; kk < 2; ++kk) {
            const int kb = kk * 32 + (lane >> 4) * 8;
            f16x8 af[4], bh[4];
#pragma unroll
            for (int mi = 0; mi < 4; ++mi)
                af[mi] = *(const f16x8*)&As[(wr * 64 + mi * 16 + (lane & 15)) * 64 + kb];
#pragma unroll
            for (int ni = 0; ni < 4; ++ni)
                bh[ni] = *(const f16x8*)&Bh[(wc * 64 + ni * 16 + (lane & 15)) * 64 + kb];
#pragma unroll
            for (int mi = 0; mi < 4; ++mi)
#pragma unroll
                for (int ni = 0; ni < 4; ++ni)
                    acc[mi][ni] = __builtin_amdgcn_mfma_f32_16x16x32_f16(
                        af[mi], bh[ni], acc[mi][ni], 0, 0, 0);
        }
        __syncthreads();
    }

    const int crow0 = m0 + wr * 64 + (lane >> 4) * 4;
    const int ccol0 = n0 + wc * 64 + (lane & 15);
    float b1[4], g2[4];
#pragma unroll
    for (int ni = 0; ni < 4; ++ni) {
        b1[ni] = g1b[ccol0 + ni * 16];
        g2[ni] = g2w[ccol0 + ni * 16];
    }
    float p[16];
#pragma unroll
    for (int mi = 0; mi < 4; ++mi)
#pragma unroll
        for (int r = 0; r < 4; ++r) {
            float s = 0.f;
#pragma unroll
            for (int ni = 0; ni < 4; ++ni) {
                float v = tanhf(acc[mi][ni][r] + b1[ni]);
                s = fmaf(v, g2[ni], s);
            }
            p[mi * 4 + r] = s;
        }
#pragma unroll
    for (int j = 0; j < 16; ++j) {
        p[j] += __shfl_xor(p[j], 1);
        p[j] += __shfl_xor(p[j], 2);
        p[j] += __shfl_xor(p[j], 4);
        p[j] += __shfl_xor(p[j], 8);
    }
    if ((lane & 15) == 0) {
#pragma unroll
        for (int j = 0; j < 16; ++j) {
            int row = crow0 + (j >> 2) * 16 + (j & 3);
            atomicAdd(&gacc[row], p[j]);
        }
    }
}

// ------------- fc1 MFMA GEMM, split-K x3, 3-term split, atomic fp32 -----------
__global__ __launch_bounds__(256) void gemm_fc1(
    const _Float16* __restrict__ Ahi, const _Float16* __restrict__ Alo,
    const _Float16* __restrict__ Whi, const _Float16* __restrict__ Wlo,
    float* __restrict__ C, int Mv, int N, int K)
{
    __shared__ _Float16 Ah[128 * 64];
    __shared__ _Float16 Al[128 * 64];
    __shared__ _Float16 Bh[128 * 64];
    __shared__ _Float16 Bl[128 * 64];
    const int tid = threadIdx.x;
    const int wave = tid >> 6, lane = tid & 63;
    const int m0 = blockIdx.y * 128, n0 = blockIdx.x * 128;
    const int kbeg = blockIdx.z * FCKSLICE;
    const int kend = kbeg + FCKSLICE;
    const int wr = wave >> 1, wc = wave & 1;

    f32x4 acc[4][4];
#pragma unroll
    for (int i = 0; i < 4; ++i)
#pragma unroll
        for (int j = 0; j < 4; ++j) acc[i][j] = (f32x4){0.f, 0.f, 0.f, 0.f};

    const int lrow = lane >> 3;
    const int lcol8 = (lane & 7) * 8;

    for (int k0 = kbeg; k0 < kend; k0 += 64) {
#pragma unroll
        for (int i = 0; i < 4; ++i) {
            int iss = wave * 4 + i;
            int row = 8 * iss + lrow;
            const _Float16* gah = Ahi + (size_t)(m0 + row) * K + k0 + lcol8;
            const _Float16* gal = Alo + (size_t)(m0 + row) * K + k0 + lcol8;
            const _Float16* gbh = Whi + (size_t)(n0 + row) * K + k0 + lcol8;
            const _Float16* gbl = Wlo + (size_t)(n0 + row) * K + k0 + lcol8;
            __builtin_amdgcn_global_load_lds(
                (const __attribute__((address_space(1))) void*)gah,
                (__attribute__((address_space(3))) void*)(Ah + iss * 512), 16, 0, 0);
            __builtin_amdgcn_global_load_lds(
                (const __attribute__((address_space(1))) void*)gal,
                (__attribute__((address_space(3))) void*)(Al + iss * 512), 16, 0, 0);
            __builtin_amdgcn_global_load_lds(
                (const __attribute__((address_space(1))) void*)gbh,
                (__attribute__((address_space(3))) void*)(Bh + iss * 512), 16, 0, 0);
            __builtin_amdgcn_global_load_lds(
                (const __attribute__((address_space(1))) void*)gbl,
                (__attribute__((address_space(3))) void*)(Bl + iss * 512), 16, 0, 0);
        }
        __syncthreads();
#pragma unroll
        for (int kk = 0; kk < 2; ++kk) {
            const int kb = kk * 32 + (lane >> 4) * 8;
            f16x8 ah[4], al[4], bh[4], bl[4];
#pragma unroll
            for (int mi = 0; mi < 4; ++mi) {
                int r = (wr * 64 + mi * 16 + (lane & 15)) * 64 + kb;
                ah[mi] = *(const f16x8*)&Ah[r];
                al[mi] = *(const f16x8*)&Al[r];
            }
#pragma unroll
            for (int ni = 0; ni < 4; ++ni) {
                int r = (wc * 64 + ni * 16 + (lane & 15)) * 64 + kb;
                bh[ni] = *(const f16x8*)&Bh[r];
                bl[ni] = *(const f16x8*)&Bl[r];
            }
#pragma unroll
            for (int mi = 0; mi < 4; ++mi)
#pragma unroll
                for (int ni = 0; ni < 4; ++ni) {
                    acc[mi][ni] = __builtin_amdgcn_mfma_f32_16x16x32_f16(
                        ah[mi], bh[ni], acc[mi][ni], 0, 0, 0);
                    acc[mi][ni] = __builtin_amdgcn_mfma_f32_16x16x32_f16(
                        ah[mi], bl[ni], acc[mi][ni], 0, 0, 0);
                    acc[mi][ni] = __builtin_amdgcn_mfma_f32_16x16x32_f16(
                        al[mi], bh[ni], acc[mi][ni], 0, 0, 0);
                }
        }
        __syncthreads();
    }

    const int crow0 = m0 + wr * 64 + (lane >> 4) * 4;
    const int ccol0 = n0 + wc * 64 + (lane & 15);
#pragma unroll
    for (int mi = 0; mi < 4; ++mi) {
#pragma unroll
        for (int ni = 0; ni < 4; ++ni) {
            int col = ccol0 + ni * 16;
#pragma unroll
            for (int r = 0; r < 4; ++r) {
                int row = crow0 + mi * 16 + r;
                if (row < Mv)
                    atomicAdd(&C[(size_t)row * N + col], acc[mi][ni][r]);
            }
        }
    }
}

// ---------------- counting sort of edges by dst ----------------
__global__ void count_k(const int* __restrict__ dst, int* __restrict__ cnt, int E)
{
    int e = blockIdx.x * blockDim.x + threadIdx.x;
    if (e < E) atomicAdd(&cnt[dst[e]], 1);
}

__global__ __launch_bounds__(256) void scan1_k(
    const int* __restrict__ cnt, int* __restrict__ offs,
    int* __restrict__ bsum, int n)
{
    __shared__ int sh[256];
    int t = threadIdx.x, idx = blockIdx.x * 256 + t;
    int v = (idx < n) ? cnt[idx] : 0;
    sh[t] = v;
    __syncthreads();
    for (int o = 1; o < 256; o <<= 1) {
        int a = (t >= o) ? sh[t - o] : 0;
        __syncthreads();
        sh[t] += a;
        __syncthreads();
    }
    if (idx < n) offs[idx] = sh[t] - v;
    if (t == 255) bsum[blockIdx.x] = sh[255];
}

__global__ __launch_bounds__(256) void scan2_k(int* __restrict__ bsum, int nb)
{
    __shared__ int sh[256];
    int t = threadIdx.x;
    int v = (t < nb) ? bsum[t] : 0;
    sh[t] = v;
    __syncthreads();
    for (int o = 1; o < 256; o <<= 1) {
        int a = (t >= o) ? sh[t - o] : 0;
        __syncthreads();
        sh[t] += a;
        __syncthreads();
    }
    if (t < nb) bsum[t] = sh[t] - v;
}

__global__ __launch_bounds__(256) void scan3_k(
    int* __restrict__ offs, const int* __restrict__ bsum,
    int* __restrict__ cursor, int n, int E)
{
    int idx = blockIdx.x * 256 + threadIdx.x;
    if (idx < n) {
        int o = offs[idx] + bsum[blockIdx.x];
        offs[idx] = o;
        cursor[idx] = o;
    }
    if (idx == 0) offs[n] = E;
}

// scatter: one fused 8B record per edge (src, ea-bits)
__global__ void scatter_k(const int* __restrict__ dst, const int* __restrict__ src,
                          const float* __restrict__ ea, int* __restrict__ cursor,
                          int2* __restrict__ esrc, int E)
{
    int e = blockIdx.x * blockDim.x + threadIdx.x;
    if (e < E) {
        int p = atomicAdd(&cursor[dst[e]], 1);
        esrc[p] = make_int2(src[e], __float_as_int(ea[e]));
    }
}

// start[g] = lower_bound(batch, g)
__global__ void start_k(const int* __restrict__ batch, int* __restrict__ start,
                        int n, int B)
{
    int g = blockIdx.x * blockDim.x + threadIdx.x;
    if (g > B) return;
    int lo = 0, hi = n;
    while (lo < hi) {
        int mid = (lo + hi) >> 1;
        if (batch[mid] < g) lo = mid + 1; else hi = mid;
    }
    start[g] = lo;
}

// ------- edge aggregation: 4-pair body, 1024-thread blocks (occupancy probe) --
__global__ __launch_bounds__(1024) void aggregate_k(
    const _Float16* __restrict__ xw, const float* __restrict__ we,
    const int2* __restrict__ esrc, const int* __restrict__ offs,
    _Float16* __restrict__ out, int n)
{
    int w = (blockIdx.x * 1024 + threadIdx.x) >> 6;
    if (w >= n) return;
    const int lane = threadIdx.x & 63;
    const int half = lane >> 5;
    const int f8 = (lane & 31) << 3;

    float we8[8];
    *(float4*)&we8[0] = *(const float4*)(we + f8);
    *(float4*)&we8[4] = *(const float4*)(we + f8 + 4);

    f16x8 xs = *(const f16x8*)(xw + (size_t)w * HIDF + f8);
    float acc[8];
#pragma unroll
    for (int j = 0; j < 8; ++j)
        acc[j] = (half == 0) ? relu_f((float)xs[j]) : 0.f;

    const int e0 = offs[w], e1 = offs[w + 1];
    const int cntE = e1 - e0;
    const int fullPairs = cntE >> 1;

    int t = 0;
    for (; t + 4 <= fullPairs; t += 4) {
        int2 p[4]; f16x8 v[4];
#pragma unroll
        for (int q = 0; q < 4; ++q) p[q] = esrc[e0 + 2 * (t + q) + half];
#pragma unroll
        for (int q = 0; q < 4; ++q)
            v[q] = *(const f16x8*)(xw + (size_t)p[q].x * HIDF + f8);
#pragma unroll
        for (int q = 0; q < 4; ++q) {
            float a = __int_as_float(p[q].y);
#pragma unroll
            for (int j = 0; j < 8; ++j)
                acc[j] += relu_f(fmaf(a, we8[j], (float)v[q][j]));
        }
    }
    for (; t < fullPairs; ++t) {
        int2 p = esrc[e0 + 2 * t + half];
        f16x8 v = *(const f16x8*)(xw + (size_t)p.x * HIDF + f8);
        float a = __int_as_float(p.y);
#pragma unroll
        for (int j = 0; j < 8; ++j)
            acc[j] += relu_f(fmaf(a, we8[j], (float)v[j]));
    }
    if ((cntE & 1) && half == 0) {
        int2 p = esrc[e1 - 1];
        f16x8 v = *(const f16x8*)(xw + (size_t)p.x * HIDF + f8);
        float a = __int_as_float(p.y);
#pragma unroll
        for (int j = 0; j < 8; ++j)
            acc[j] += relu_f(fmaf(a, we8[j], (float)v[j]));
    }

#pragma unroll
    for (int j = 0; j < 8; ++j)
        acc[j] += __shfl_xor(acc[j], 32);

    if (half == 0) {
        f16x8 o;
#pragma unroll
        for (int j = 0; j < 8; ++j) o[j] = (_Float16)acc[j];
        *(f16x8*)(out + (size_t)w * HIDF + f8) = o;
    }
}

// ---------------- pooling with fused sigmoid gate ----------------
__global__ __launch_bounds__(256) void pool_k(
    const _Float16* __restrict__ x, const float* __restrict__ gacc,
    const float* __restrict__ g2b, const int* __restrict__ start,
    float* __restrict__ pooled, int B)
{
    int w = (blockIdx.x * blockDim.x + threadIdx.x) >> 6;
    if (w >= B) return;
    int lane = threadIdx.x & 63;
    int f = lane << 2;
    float b0 = g2b[0];
    float4 acc = make_float4(0.f, 0.f, 0.f, 0.f);
    int i0 = start[w], i1 = start[w + 1];
    for (int i = i0; i < i1; ++i) {
        float gi = 1.f / (1.f + expf(-(gacc[i] + b0)));
        f16x4 v = *(const f16x4*)(x + (size_t)i * HIDF + f);
        acc.x = fmaf(gi, (float)v[0], acc.x);
        acc.y = fmaf(gi, (float)v[1], acc.y);
        acc.z = fmaf(gi, (float)v[2], acc.z);
        acc.w = fmaf(gi, (float)v[3], acc.w);
    }
    *(float4*)(pooled + (size_t)w * HIDF + f) = acc;
}

// ---------------- BN stats per column (fc1 bias folded here) ------------------
__global__ __launch_bounds__(256) void bnstats_k(
    const float* __restrict__ h, const float* __restrict__ fc1b,
    float* __restrict__ mu, float* __restrict__ rs, int B)
{
    int j = blockIdx.x;
    int tid = threadIdx.x;
    float bj = fc1b[j];
    float s = 0.f, s2 = 0.f;
    for (int g = tid; g < B; g += 256) {
        float v = h[(size_t)g * HIDF + j] + bj;
        s += v;
        s2 = fmaf(v, v, s2);
    }
    __shared__ float sh[256], sh2[256];
    sh[tid] = s; sh2[tid] = s2;
    __syncthreads();
    for (int o = 128; o; o >>= 1) {
        if (tid < o) { sh[tid] += sh[tid + o]; sh2[tid] += sh2[tid + o]; }
        __syncthreads();
    }
    if (tid == 0) {
        float m = sh[0] / (float)B;
        float var = sh2[0] / (float)B - m * m;
        if (var < 0.f) var = 0.f;
        mu[j] = m;
        rs[j] = rsqrtf(var + 1e-5f);
    }
}

// ---------------- final ----------------
__global__ __launch_bounds__(256) void final_k(
    const float* __restrict__ h, const float* __restrict__ fc1b,
    const float* __restrict__ mu, const float* __restrict__ rs,
    const float* __restrict__ gamma, const float* __restrict__ beta,
    const float* __restrict__ w2, const float* __restrict__ b2,
    float* __restrict__ out, int B)
{
    int g = blockIdx.x;
    int j = threadIdx.x;
    float v = h[(size_t)g * HIDF + j] + fc1b[j];
    v = (v - mu[j]) * rs[j] * gamma[j] + beta[j];
    v = relu_f(v);
    float term = v * w2[j];
    __shared__ float sh[256];
    sh[j] = term;
    __syncthreads();
    for (int o = 128; o; o >>= 1) {
        if (j < o) sh[j] += sh[j + o];
        __syncthreads();
    }
    if (j == 0) out[g] = sh[0] + b2[0];
}

extern "C" void kernel_launch(void* const* d_in, const int* in_sizes, int n_in,
                              void* d_out, int out_size, void* d_ws, size_t ws_size,
                              hipStream_t stream)
{
    const float* x      = (const float*)d_in[0];
    const int*   ei     = (const int*)d_in[1];
    const float* ea     = (const float*)d_in[2];
    const float* fp     = (const float*)d_in[3];
    const int*   batch  = (const int*)d_in[4];
    const float* lin_w  = (const float*)d_in[5];
    const float* lin_b  = (const float*)d_in[6];
    const float* upd_w  = (const float*)d_in[7];
    const float* upd_b  = (const float*)d_in[8];
    const float* g1w    = (const float*)d_in[9];
    const float* g1b    = (const float*)d_in[10];
    const float* g2w    = (const float*)d_in[11];
    const float* g2b    = (const float*)d_in[12];
    const float* fc1w   = (const float*)d_in[13];
    const float* fc1b   = (const float*)d_in[14];
    const float* gamma  = (const float*)d_in[15];
    const float* beta   = (const float*)d_in[16];
    const float* fc2w   = (const float*)d_in[17];
    const float* fc2b   = (const float*)d_in[18];
    float* out = (float*)d_out;

    const int n = in_sizes[0] / HIDF;        // 50000
    const int E = in_sizes[1] / 2;           // 800000
    const int B = in_sizes[3] / FPDIM;       // 2000
    const int L = in_sizes[5] / (257 * 256); // 4
    const int* srcArr = ei;
    const int* dstArr = ei + E;
    const int nb = (n + 255) / 256;

    // ---- workspace layout ----
    char* w = (char*)d_ws;
    _Float16* xh   = (_Float16*)w;  w += (size_t)MPAD * HIDF * 2;
    _Float16* bufA = (_Float16*)w;  w += (size_t)MPAD * HIDF * 2;
    _Float16* bufB = (_Float16*)w;  w += (size_t)MPAD * HIDF * 2;
    _Float16* whi = (_Float16*)w;  w += (size_t)9 * 65536 * 2;
    _Float16* wlo = (_Float16*)w;  w += (size_t)9 * 65536 * 2;
    _Float16* fahi = (_Float16*)w; w += (size_t)FCM * FCK * 2;
    _Float16* falo = (_Float16*)w; w += (size_t)FCM * FCK * 2;
    _Float16* fwhi = (_Float16*)w; w += (size_t)HIDF * FCK * 2;
    _Float16* fwlo = (_Float16*)w; w += (size_t)HIDF * FCK * 2;
    int2*  esrc   = (int2*)w;   w += (size_t)E * 8;
    int*   offs   = (int*)w;    w += ((size_t)n + 4) * 4;
    int*   cursor = (int*)w;    w += ((size_t)n + 4) * 4;
    int*   cnt    = (int*)w;    w += (size_t)n * 4;
    int*   bsum   = (int*)w;    w += 256 * 4;
    int*   startA = (int*)w;    w += ((size_t)B + 4) * 4;
    float* gacc   = (float*)w;  w += (size_t)MPAD * 4;
    float* pooled = (float*)w;  w += (size_t)B * HIDF * 4;
    float* h      = (float*)w;  w += (size_t)B * HIDF * 4;
    float* mu     = (float*)w;  w += 256 * 4;
    float* rs     = (float*)w;  w += 256 * 4;

    // ---- CSR build (counting sort by dst) + batch starts ----
    hipMemsetAsync(cnt, 0, (size_t)n * 4, stream);
    count_k<<<(E + 255) / 256, 256, 0, stream>>>(dstArr, cnt, E);
    scan1_k<<<nb, 256, 0, stream>>>(cnt, offs, bsum, n);
    scan2_k<<<1, 256, 0, stream>>>(bsum, nb);
    scan3_k<<<nb, 256, 0, stream>>>(offs, bsum, cursor, n, E);
    scatter_k<<<(E + 255) / 256, 256, 0, stream>>>(dstArr, srcArr, ea, cursor, esrc, E);
    start_k<<<(B + 256) / 256, 256, 0, stream>>>(batch, startA, n, B);

    // ---- input fp16 conversion + merged weight split ----
    convxh_k<<<(MPAD * 64 + 255) / 256, 256, 0, stream>>>(x, xh, n);
    dim3 gcw((HIDF * FCK + 255) / 256, 10);
    convw_all_k<<<gcw, 256, 0, stream>>>(lin_w, upd_w, g1w, fc1w, whi, wlo, fwhi, fwlo);
    hipMemsetAsync(gacc, 0, (size_t)MPAD * 4, stream);

    // ---- message passing (both GEMMs 2-term) ----
    dim3 ggm(HIDF / 128, MPAD / 128);
    const int aggBlocks = (n * 64 + 1023) / 1024;
    for (int l = 0; l < L; ++l) {
        const float* we = lin_w + (size_t)l * 257 * 256 + 256 * 256;
        const float* lb = lin_b + (size_t)l * 256;
        gemm_f16<0, 2><<<ggm, 256, 0, stream>>>(xh, whi + (size_t)l * 65536,
                                                wlo + (size_t)l * 65536, lb,
                                                bufA, MPAD, HIDF, HIDF);
        aggregate_k<<<aggBlocks, 1024, 0, stream>>>(
            bufA, we, esrc, offs, bufB, n);
        gemm_f16<1, 2><<<ggm, 256, 0, stream>>>(bufB, whi + (size_t)(4 + l) * 65536,
                                                wlo + (size_t)(4 + l) * 65536,
                                                upd_b + (size_t)l * 256, xh, MPAD, HIDF, HIDF);
    }

    // ---- gating (fused dot, 1-term) + pooling (fused sigmoid) ----
    gemm_gate<<<ggm, 256, 0, stream>>>(xh, whi + (size_t)8 * 65536,
                                       g1b, g2w, gacc, MPAD, HIDF, HIDF);
    pool_k<<<(B * 64 + 255) / 256, 256, 0, stream>>>(xh, gacc, g2b, startA, pooled, B);

    // ---- head: fc1 split-K MFMA (atomic fp32 into zeroed h), BN, final ----
    convfc1a_k<<<(FCM * FCK + 255) / 256, 256, 0, stream>>>(pooled, fp, fahi, falo, B);
    hipMemsetAsync(h, 0, (size_t)B * HIDF * 4, stream);
    dim3 ggf(HIDF / 128, FCM / 128, FCSLICES);
    gemm_fc1<<<ggf, 256, 0, stream>>>(fahi, falo, fwhi, fwlo, h, B, HIDF, FCK);
    bnstats_k<<<256, 256, 0, stream>>>(h, fc1b, mu, rs, B);
    final_k<<<B, 256, 0, stream>>>(h, fc1b, mu, rs, gamma, beta, fc2w, fc2b, out, B);
}

// Round 13
// 668.167 us; speedup vs baseline: 1.0712x; 1.0712x over previous
//
#include <hip/hip_runtime.h>
#include <math.h>

#define HIDF 256
#define FPDIM 1034
#define MPAD 50048     // 50000 rounded up to 128
#define FCM 2048       // fc1 M pad (B=2000)
#define FCK 1344       // fc1 K pad (1290 -> 21*64)
#define FCSLICES 3
#define FCKSLICE 448   // 7 K-steps per slice

typedef _Float16 f16x8 __attribute__((ext_vector_type(8)));
typedef _Float16 f16x4 __attribute__((ext_vector_type(4)));
typedef float f32x4 __attribute__((ext_vector_type(4)));

__device__ __forceinline__ float relu_f(float v) { return fmaxf(v, 0.f); }

// ---------------- x fp32 -> fp16 [MPAD][256], zero pad ----------------
__global__ __launch_bounds__(256) void convxh_k(
    const float* __restrict__ x, _Float16* __restrict__ xh, int n)
{
    int i = blockIdx.x * 256 + threadIdx.x;
    int row = i >> 6;
    if (row >= MPAD) return;
    f16x4 o;
    if (row < n) {
        float4 v = ((const float4*)x)[i];
        o[0] = (_Float16)v.x; o[1] = (_Float16)v.y;
        o[2] = (_Float16)v.z; o[3] = (_Float16)v.w;
    } else {
        o[0] = o[1] = o[2] = o[3] = (_Float16)0.f;
    }
    ((f16x4*)xh)[i] = o;
}

// ---- merged weight split: y<9 square weights -> whi/wlo; y==9 fc1w -----------
__global__ __launch_bounds__(256) void convw_all_k(
    const float* __restrict__ lin_w, const float* __restrict__ upd_w,
    const float* __restrict__ g1w, const float* __restrict__ fc1w,
    _Float16* __restrict__ whi, _Float16* __restrict__ wlo,
    _Float16* __restrict__ fwhi, _Float16* __restrict__ fwlo)
{
    int m = blockIdx.y;
    int i = blockIdx.x * 256 + threadIdx.x;
    if (m < 9) {
        if (i >= 65536) return;
        const float* src = (m < 4) ? (lin_w + (size_t)m * 257 * 256)
                         : (m < 8) ? (upd_w + (size_t)(m - 4) * 65536)
                                   : g1w;
        int nn = i >> 8, kk = i & 255;
        float v = src[kk * 256 + nn];
        _Float16 h = (_Float16)v;
        _Float16 l = (_Float16)(v - (float)h);
        whi[(size_t)m * 65536 + i] = h;
        wlo[(size_t)m * 65536 + i] = l;
    } else {
        if (i >= HIDF * FCK) return;
        int nn = i / FCK, kk = i - nn * FCK;
        float v = (kk < HIDF + FPDIM) ? fc1w[(size_t)kk * HIDF + nn] : 0.f;
        _Float16 h = (_Float16)v;
        _Float16 l = (_Float16)(v - (float)h);
        fwhi[i] = h;
        fwlo[i] = l;
    }
}

// ------- fc1 input: [pooled | fp] -> split fp16 hi/lo [FCM][FCK] --------------
__global__ __launch_bounds__(256) void convfc1a_k(
    const float* __restrict__ pooled, const float* __restrict__ fp,
    _Float16* __restrict__ ahi, _Float16* __restrict__ alo, int B)
{
    int i = blockIdx.x * 256 + threadIdx.x;
    if (i >= FCM * FCK) return;
    int row = i / FCK, col = i - row * FCK;
    float v = 0.f;
    if (row < B) {
        if (col < HIDF) v = pooled[(size_t)row * HIDF + col];
        else if (col < HIDF + FPDIM) v = fp[(size_t)row * FPDIM + (col - HIDF)];
    }
    _Float16 h = (_Float16)v;
    _Float16 l = (_Float16)(v - (float)h);
    ahi[i] = h;
    alo[i] = l;
}

// ---------------- fp16 MFMA GEMM: C = act(A @ W^T + bias), fp16 out -----------
// BM=BN=128, BK=64, 4 waves (2x2 of 64x64), mfma_f32_16x16x32_f16.
// TERMS=2: acc = A*Whi + A*Wlo (~22-bit weights). TERMS=1: pure fp16 weights.
template <int ACT, int TERMS>
__global__ __launch_bounds__(256) void gemm_f16(
    const _Float16* __restrict__ A, const _Float16* __restrict__ Whi,
    const _Float16* __restrict__ Wlo, const float* __restrict__ bias,
    _Float16* __restrict__ C, int M, int N, int K)
{
    __shared__ _Float16 As[128 * 64];
    __shared__ _Float16 Bh[128 * 64];
    __shared__ _Float16 Bl[(TERMS == 2) ? 128 * 64 : 64];
    const int tid = threadIdx.x;
    const int wave = tid >> 6, lane = tid & 63;
    const int m0 = blockIdx.y * 128, n0 = blockIdx.x * 128;
    const int wr = wave >> 1, wc = wave & 1;

    f32x4 acc[4][4];
#pragma unroll
    for (int i = 0; i < 4; ++i)
#pragma unroll
        for (int j = 0; j < 4; ++j) acc[i][j] = (f32x4){0.f, 0.f, 0.f, 0.f};

    const int lrow = lane >> 3;
    const int lcol8 = (lane & 7) * 8;

    for (int k0 = 0; k0 < K; k0 += 64) {
#pragma unroll
        for (int i = 0; i < 4; ++i) {
            int iss = wave * 4 + i;
            int row = 8 * iss + lrow;
            const _Float16* ga = A   + (size_t)(m0 + row) * K + k0 + lcol8;
            const _Float16* gh = Whi + (size_t)(n0 + row) * K + k0 + lcol8;
            __builtin_amdgcn_global_load_lds(
                (const __attribute__((address_space(1))) void*)ga,
                (__attribute__((address_space(3))) void*)(As + iss * 512), 16, 0, 0);
            __builtin_amdgcn_global_load_lds(
                (const __attribute__((address_space(1))) void*)gh,
                (__attribute__((address_space(3))) void*)(Bh + iss * 512), 16, 0, 0);
            if constexpr (TERMS == 2) {
                const _Float16* gl = Wlo + (size_t)(n0 + row) * K + k0 + lcol8;
                __builtin_amdgcn_global_load_lds(
                    (const __attribute__((address_space(1))) void*)gl,
                    (__attribute__((address_space(3))) void*)(Bl + iss * 512), 16, 0, 0);
            }
        }
        __syncthreads();
#pragma unroll
        for (int kk = 0; kk < 2; ++kk) {
            const int kb = kk * 32 + (lane >> 4) * 8;
            f16x8 af[4], bh[4], bl[4];
#pragma unroll
            for (int mi = 0; mi < 4; ++mi)
                af[mi] = *(const f16x8*)&As[(wr * 64 + mi * 16 + (lane & 15)) * 64 + kb];
#pragma unroll
            for (int ni = 0; ni < 4; ++ni) {
                int r = (wc * 64 + ni * 16 + (lane & 15)) * 64 + kb;
                bh[ni] = *(const f16x8*)&Bh[r];
                if constexpr (TERMS == 2) bl[ni] = *(const f16x8*)&Bl[r];
            }
#pragma unroll
            for (int mi = 0; mi < 4; ++mi)
#pragma unroll
                for (int ni = 0; ni < 4; ++ni) {
                    acc[mi][ni] = __builtin_amdgcn_mfma_f32_16x16x32_f16(
                        af[mi], bh[ni], acc[mi][ni], 0, 0, 0);
                    if constexpr (TERMS == 2)
                        acc[mi][ni] = __builtin_amdgcn_mfma_f32_16x16x32_f16(
                            af[mi], bl[ni], acc[mi][ni], 0, 0, 0);
                }
        }
        __syncthreads();
    }

    const int crow0 = m0 + wr * 64 + (lane >> 4) * 4;
    const int ccol0 = n0 + wc * 64 + (lane & 15);
#pragma unroll
    for (int mi = 0; mi < 4; ++mi) {
#pragma unroll
        for (int ni = 0; ni < 4; ++ni) {
            int col = ccol0 + ni * 16;
            float bv = bias ? bias[col] : 0.f;
#pragma unroll
            for (int r = 0; r < 4; ++r) {
                int row = crow0 + mi * 16 + r;
                float v = acc[mi][ni][r] + bv;
                if (ACT == 1) v = relu_f(v);
                C[(size_t)row * N + col] = (_Float16)v;
            }
        }
    }
}

// ------- fused gate GEMM (1-term): gacc[row] += dot(tanh(A@g1w^T+g1b), g2w) ---
__global__ __launch_bounds__(256) void gemm_gate(
    const _Float16* __restrict__ A, const _Float16* __restrict__ Whi,
    const float* __restrict__ g1b, const float* __restrict__ g2w,
    float* __restrict__ gacc, int M, int N, int K)
{
    __shared__ _Float16 As[128 * 64];
    __shared__ _Float16 Bh[128 * 64];
    const int tid = threadIdx.x;
    const int wave = tid >> 6, lane = tid & 63;
    const int m0 = blockIdx.y * 128, n0 = blockIdx.x * 128;
    const int wr = wave >> 1, wc = wave & 1;

    f32x4 acc[4][4];
#pragma unroll
    for (int i = 0; i < 4; ++i)
#pragma unroll
        for (int j = 0; j < 4; ++j) acc[i][j] = (f32x4){0.f, 0.f, 0.f, 0.f};

    const int lrow = lane >> 3;
    const int lcol8 = (lane & 7) * 8;

    for (int k0 = 0; k0 < K; k0 += 64) {
#pragma unroll
        for (int i = 0; i < 4; ++i) {
            int iss = wave * 4 + i;
            int row = 8 * iss + lrow;
            const _Float16* ga = A   + (size_t)(m0 + row) * K + k0 + lcol8;
            const _Float16* gh = Whi + (size_t)(n0 + row) * K + k0 + lcol8;
            __builtin_amdgcn_global_load_lds(
                (const __attribute__((address_space(1))) void*)ga,
                (__attribute__((address_space(3))) void*)(As + iss * 512), 16, 0, 0);
            __builtin_amdgcn_global_load_lds(
                (const __attribute__((address_space(1))) void*)gh,
                (__attribute__((address_space(3))) void*)(Bh + iss * 512), 16, 0, 0);
        }
        __syncthreads();
#pragma unroll
        for (int kk = 0; kk < 2; ++kk) {
            const int kb = kk * 32 + (lane >> 4) * 8;
            f16x8 af[4], bh[4];
#pragma unroll
            for (int mi = 0; mi < 4; ++mi)
                af[mi] = *(const f16x8*)&As[(wr * 64 + mi * 16 + (lane & 15)) * 64 + kb];
#pragma unroll
            for (int ni = 0; ni < 4; ++ni)
                bh[ni] = *(const f16x8*)&Bh[(wc * 64 + ni * 16 + (lane & 15)) * 64 + kb];
#pragma unroll
            for (int mi = 0; mi < 4; ++mi)
#pragma unroll
                for (int ni = 0; ni < 4; ++ni)
                    acc[mi][ni] = __builtin_amdgcn_mfma_f32_16x16x32_f16(
                        af[mi], bh[ni], acc[mi][ni], 0, 0, 0);
        }
        __syncthreads();
    }

    const int crow0 = m0 + wr * 64 + (lane >> 4) * 4;
    const int ccol0 = n0 + wc * 64 + (lane & 15);
    float b1[4], g2[4];
#pragma unroll
    for (int ni = 0; ni < 4; ++ni) {
        b1[ni] = g1b[ccol0 + ni * 16];
        g2[ni] = g2w[ccol0 + ni * 16];
    }
    float p[16];
#pragma unroll
    for (int mi = 0; mi < 4; ++mi)
#pragma unroll
        for (int r = 0; r < 4; ++r) {
            float s = 0.f;
#pragma unroll
            for (int ni = 0; ni < 4; ++ni) {
                float v = tanhf(acc[mi][ni][r] + b1[ni]);
                s = fmaf(v, g2[ni], s);
            }
            p[mi * 4 + r] = s;
        }
#pragma unroll
    for (int j = 0; j < 16; ++j) {
        p[j] += __shfl_xor(p[j], 1);
        p[j] += __shfl_xor(p[j], 2);
        p[j] += __shfl_xor(p[j], 4);
        p[j] += __shfl_xor(p[j], 8);
    }
    if ((lane & 15) == 0) {
#pragma unroll
        for (int j = 0; j < 16; ++j) {
            int row = crow0 + (j >> 2) * 16 + (j & 3);
            atomicAdd(&gacc[row], p[j]);
        }
    }
}

// ------------- fc1 MFMA GEMM, split-K x3, 3-term split, atomic fp32 -----------
__global__ __launch_bounds__(256) void gemm_fc1(
    const _Float16* __restrict__ Ahi, const _Float16* __restrict__ Alo,
    const _Float16* __restrict__ Whi, const _Float16* __restrict__ Wlo,
    float* __restrict__ C, int Mv, int N, int K)
{
    __shared__ _Float16 Ah[128 * 64];
    __shared__ _Float16 Al[128 * 64];
    __shared__ _Float16 Bh[128 * 64];
    __shared__ _Float16 Bl[128 * 64];
    const int tid = threadIdx.x;
    const int wave = tid >> 6, lane = tid & 63;
    const int m0 = blockIdx.y * 128, n0 = blockIdx.x * 128;
    const int kbeg = blockIdx.z * FCKSLICE;
    const int kend = kbeg + FCKSLICE;
    const int wr = wave >> 1, wc = wave & 1;

    f32x4 acc[4][4];
#pragma unroll
    for (int i = 0; i < 4; ++i)
#pragma unroll
        for (int j = 0; j < 4; ++j) acc[i][j] = (f32x4){0.f, 0.f, 0.f, 0.f};

    const int lrow = lane >> 3;
    const int lcol8 = (lane & 7) * 8;

    for (int k0 = kbeg; k0 < kend; k0 += 64) {
#pragma unroll
        for (int i = 0; i < 4; ++i) {
            int iss = wave * 4 + i;
            int row = 8 * iss + lrow;
            const _Float16* gah = Ahi + (size_t)(m0 + row) * K + k0 + lcol8;
            const _Float16* gal = Alo + (size_t)(m0 + row) * K + k0 + lcol8;
            const _Float16* gbh = Whi + (size_t)(n0 + row) * K + k0 + lcol8;
            const _Float16* gbl = Wlo + (size_t)(n0 + row) * K + k0 + lcol8;
            __builtin_amdgcn_global_load_lds(
                (const __attribute__((address_space(1))) void*)gah,
                (__attribute__((address_space(3))) void*)(Ah + iss * 512), 16, 0, 0);
            __builtin_amdgcn_global_load_lds(
                (const __attribute__((address_space(1))) void*)gal,
                (__attribute__((address_space(3))) void*)(Al + iss * 512), 16, 0, 0);
            __builtin_amdgcn_global_load_lds(
                (const __attribute__((address_space(1))) void*)gbh,
                (__attribute__((address_space(3))) void*)(Bh + iss * 512), 16, 0, 0);
            __builtin_amdgcn_global_load_lds(
                (const __attribute__((address_space(1))) void*)gbl,
                (__attribute__((address_space(3))) void*)(Bl + iss * 512), 16, 0, 0);
        }
        __syncthreads();
#pragma unroll
        for (int kk = 0; kk < 2; ++kk) {
            const int kb = kk * 32 + (lane >> 4) * 8;
            f16x8 ah[4], al[4], bh[4], bl[4];
#pragma unroll
            for (int mi = 0; mi < 4; ++mi) {
                int r = (wr * 64 + mi * 16 + (lane & 15)) * 64 + kb;
                ah[mi] = *(const f16x8*)&Ah[r];
                al[mi] = *(const f16x8*)&Al[r];
            }
#pragma unroll
            for (int ni = 0; ni < 4; ++ni) {
                int r = (wc * 64 + ni * 16 + (lane & 15)) * 64 + kb;
                bh[ni] = *(const f16x8*)&Bh[r];
                bl[ni] = *(const f16x8*)&Bl[r];
            }
#pragma unroll
            for (int mi = 0; mi < 4; ++mi)
#pragma unroll
                for (int ni = 0; ni < 4; ++ni) {
                    acc[mi][ni] = __builtin_amdgcn_mfma_f32_16x16x32_f16(
                        ah[mi], bh[ni], acc[mi][ni], 0, 0, 0);
                    acc[mi][ni] = __builtin_amdgcn_mfma_f32_16x16x32_f16(
                        ah[mi], bl[ni], acc[mi][ni], 0, 0, 0);
                    acc[mi][ni] = __builtin_amdgcn_mfma_f32_16x16x32_f16(
                        al[mi], bh[ni], acc[mi][ni], 0, 0, 0);
                }
        }
        __syncthreads();
    }

    const int crow0 = m0 + wr * 64 + (lane >> 4) * 4;
    const int ccol0 = n0 + wc * 64 + (lane & 15);
#pragma unroll
    for (int mi = 0; mi < 4; ++mi) {
#pragma unroll
        for (int ni = 0; ni < 4; ++ni) {
            int col = ccol0 + ni * 16;
#pragma unroll
            for (int r = 0; r < 4; ++r) {
                int row = crow0 + mi * 16 + r;
                if (row < Mv)
                    atomicAdd(&C[(size_t)row * N + col], acc[mi][ni][r]);
            }
        }
    }
}

// ---------------- counting sort of edges by dst ----------------
__global__ void count_k(const int* __restrict__ dst, int* __restrict__ cnt, int E)
{
    int e = blockIdx.x * blockDim.x + threadIdx.x;
    if (e < E) atomicAdd(&cnt[dst[e]], 1);
}

__global__ __launch_bounds__(256) void scan1_k(
    const int* __restrict__ cnt, int* __restrict__ offs,
    int* __restrict__ bsum, int n)
{
    __shared__ int sh[256];
    int t = threadIdx.x, idx = blockIdx.x * 256 + t;
    int v = (idx < n) ? cnt[idx] : 0;
    sh[t] = v;
    __syncthreads();
    for (int o = 1; o < 256; o <<= 1) {
        int a = (t >= o) ? sh[t - o] : 0;
        __syncthreads();
        sh[t] += a;
        __syncthreads();
    }
    if (idx < n) offs[idx] = sh[t] - v;
    if (t == 255) bsum[blockIdx.x] = sh[255];
}

__global__ __launch_bounds__(256) void scan2_k(int* __restrict__ bsum, int nb)
{
    __shared__ int sh[256];
    int t = threadIdx.x;
    int v = (t < nb) ? bsum[t] : 0;
    sh[t] = v;
    __syncthreads();
    for (int o = 1; o < 256; o <<= 1) {
        int a = (t >= o) ? sh[t - o] : 0;
        __syncthreads();
        sh[t] += a;
        __syncthreads();
    }
    if (t < nb) bsum[t] = sh[t] - v;
}

__global__ __launch_bounds__(256) void scan3_k(
    int* __restrict__ offs, const int* __restrict__ bsum,
    int* __restrict__ cursor, int n, int E)
{
    int idx = blockIdx.x * 256 + threadIdx.x;
    if (idx < n) {
        int o = offs[idx] + bsum[blockIdx.x];
        offs[idx] = o;
        cursor[idx] = o;
    }
    if (idx == 0) offs[n] = E;
}

// scatter: one fused 8B record per edge (src, ea-bits)
__global__ void scatter_k(const int* __restrict__ dst, const int* __restrict__ src,
                          const float* __restrict__ ea, int* __restrict__ cursor,
                          int2* __restrict__ esrc, int E)
{
    int e = blockIdx.x * blockDim.x + threadIdx.x;
    if (e < E) {
        int p = atomicAdd(&cursor[dst[e]], 1);
        esrc[p] = make_int2(src[e], __float_as_int(ea[e]));
    }
}

// start[g] = lower_bound(batch, g)
__global__ void start_k(const int* __restrict__ batch, int* __restrict__ start,
                        int n, int B)
{
    int g = blockIdx.x * blockDim.x + threadIdx.x;
    if (g > B) return;
    int lo = 0, hi = n;
    while (lo < hi) {
        int mid = (lo + hi) >> 1;
        if (batch[mid] < g) lo = mid + 1; else hi = mid;
    }
    start[g] = lo;
}

// ------- edge aggregation: measured-best (4-pair, 256 threads, VGPR 40) -------
__global__ __launch_bounds__(256) void aggregate_k(
    const _Float16* __restrict__ xw, const float* __restrict__ we,
    const int2* __restrict__ esrc, const int* __restrict__ offs,
    _Float16* __restrict__ out, int n)
{
    int w = (blockIdx.x * blockDim.x + threadIdx.x) >> 6;
    if (w >= n) return;
    const int lane = threadIdx.x & 63;
    const int half = lane >> 5;
    const int f8 = (lane & 31) << 3;

    float we8[8];
    *(float4*)&we8[0] = *(const float4*)(we + f8);
    *(float4*)&we8[4] = *(const float4*)(we + f8 + 4);

    f16x8 xs = *(const f16x8*)(xw + (size_t)w * HIDF + f8);
    float acc[8];
#pragma unroll
    for (int j = 0; j < 8; ++j)
        acc[j] = (half == 0) ? relu_f((float)xs[j]) : 0.f;

    const int e0 = offs[w], e1 = offs[w + 1];
    const int cntE = e1 - e0;
    const int fullPairs = cntE >> 1;

    int t = 0;
    for (; t + 4 <= fullPairs; t += 4) {
        int2 p[4]; f16x8 v[4];
#pragma unroll
        for (int q = 0; q < 4; ++q) p[q] = esrc[e0 + 2 * (t + q) + half];
#pragma unroll
        for (int q = 0; q < 4; ++q)
            v[q] = *(const f16x8*)(xw + (size_t)p[q].x * HIDF + f8);
#pragma unroll
        for (int q = 0; q < 4; ++q) {
            float a = __int_as_float(p[q].y);
#pragma unroll
            for (int j = 0; j < 8; ++j)
                acc[j] += relu_f(fmaf(a, we8[j], (float)v[q][j]));
        }
    }
    for (; t < fullPairs; ++t) {
        int2 p = esrc[e0 + 2 * t + half];
        f16x8 v = *(const f16x8*)(xw + (size_t)p.x * HIDF + f8);
        float a = __int_as_float(p.y);
#pragma unroll
        for (int j = 0; j < 8; ++j)
            acc[j] += relu_f(fmaf(a, we8[j], (float)v[j]));
    }
    if ((cntE & 1) && half == 0) {
        int2 p = esrc[e1 - 1];
        f16x8 v = *(const f16x8*)(xw + (size_t)p.x * HIDF + f8);
        float a = __int_as_float(p.y);
#pragma unroll
        for (int j = 0; j < 8; ++j)
            acc[j] += relu_f(fmaf(a, we8[j], (float)v[j]));
    }

#pragma unroll
    for (int j = 0; j < 8; ++j)
        acc[j] += __shfl_xor(acc[j], 32);

    if (half == 0) {
        f16x8 o;
#pragma unroll
        for (int j = 0; j < 8; ++j) o[j] = (_Float16)acc[j];
        *(f16x8*)(out + (size_t)w * HIDF + f8) = o;
    }
}

// ---------------- pooling with fused sigmoid gate ----------------
__global__ __launch_bounds__(256) void pool_k(
    const _Float16* __restrict__ x, const float* __restrict__ gacc,
    const float* __restrict__ g2b, const int* __restrict__ start,
    float* __restrict__ pooled, int B)
{
    int w = (blockIdx.x * blockDim.x + threadIdx.x) >> 6;
    if (w >= B) return;
    int lane = threadIdx.x & 63;
    int f = lane << 2;
    float b0 = g2b[0];
    float4 acc = make_float4(0.f, 0.f, 0.f, 0.f);
    int i0 = start[w], i1 = start[w + 1];
    for (int i = i0; i < i1; ++i) {
        float gi = 1.f / (1.f + expf(-(gacc[i] + b0)));
        f16x4 v = *(const f16x4*)(x + (size_t)i * HIDF + f);
        acc.x = fmaf(gi, (float)v[0], acc.x);
        acc.y = fmaf(gi, (float)v[1], acc.y);
        acc.z = fmaf(gi, (float)v[2], acc.z);
        acc.w = fmaf(gi, (float)v[3], acc.w);
    }
    *(float4*)(pooled + (size_t)w * HIDF + f) = acc;
}

// ---------------- BN stats per column (fc1 bias folded here) ------------------
__global__ __launch_bounds__(256) void bnstats_k(
    const float* __restrict__ h, const float* __restrict__ fc1b,
    float* __restrict__ mu, float* __restrict__ rs, int B)
{
    int j = blockIdx.x;
    int tid = threadIdx.x;
    float bj = fc1b[j];
    float s = 0.f, s2 = 0.f;
    for (int g = tid; g < B; g += 256) {
        float v = h[(size_t)g * HIDF + j] + bj;
        s += v;
        s2 = fmaf(v, v, s2);
    }
    __shared__ float sh[256], sh2[256];
    sh[tid] = s; sh2[tid] = s2;
    __syncthreads();
    for (int o = 128; o; o >>= 1) {
        if (tid < o) { sh[tid] += sh[tid + o]; sh2[tid] += sh2[tid + o]; }
        __syncthreads();
    }
    if (tid == 0) {
        float m = sh[0] / (float)B;
        float var = sh2[0] / (float)B - m * m;
        if (var < 0.f) var = 0.f;
        mu[j] = m;
        rs[j] = rsqrtf(var + 1e-5f);
    }
}

// ---------------- final ----------------
__global__ __launch_bounds__(256) void final_k(
    const float* __restrict__ h, const float* __restrict__ fc1b,
    const float* __restrict__ mu, const float* __restrict__ rs,
    const float* __restrict__ gamma, const float* __restrict__ beta,
    const float* __restrict__ w2, const float* __restrict__ b2,
    float* __restrict__ out, int B)
{
    int g = blockIdx.x;
    int j = threadIdx.x;
    float v = h[(size_t)g * HIDF + j] + fc1b[j];
    v = (v - mu[j]) * rs[j] * gamma[j] + beta[j];
    v = relu_f(v);
    float term = v * w2[j];
    __shared__ float sh[256];
    sh[j] = term;
    __syncthreads();
    for (int o = 128; o; o >>= 1) {
        if (j < o) sh[j] += sh[j + o];
        __syncthreads();
    }
    if (j == 0) out[g] = sh[0] + b2[0];
}

extern "C" void kernel_launch(void* const* d_in, const int* in_sizes, int n_in,
                              void* d_out, int out_size, void* d_ws, size_t ws_size,
                              hipStream_t stream)
{
    const float* x      = (const float*)d_in[0];
    const int*   ei     = (const int*)d_in[1];
    const float* ea     = (const float*)d_in[2];
    const float* fp     = (const float*)d_in[3];
    const int*   batch  = (const int*)d_in[4];
    const float* lin_w  = (const float*)d_in[5];
    const float* lin_b  = (const float*)d_in[6];
    const float* upd_w  = (const float*)d_in[7];
    const float* upd_b  = (const float*)d_in[8];
    const float* g1w    = (const float*)d_in[9];
    const float* g1b    = (const float*)d_in[10];
    const float* g2w    = (const float*)d_in[11];
    const float* g2b    = (const float*)d_in[12];
    const float* fc1w   = (const float*)d_in[13];
    const float* fc1b   = (const float*)d_in[14];
    const float* gamma  = (const float*)d_in[15];
    const float* beta   = (const float*)d_in[16];
    const float* fc2w   = (const float*)d_in[17];
    const float* fc2b   = (const float*)d_in[18];
    float* out = (float*)d_out;

    const int n = in_sizes[0] / HIDF;        // 50000
    const int E = in_sizes[1] / 2;           // 800000
    const int B = in_sizes[3] / FPDIM;       // 2000
    const int L = in_sizes[5] / (257 * 256); // 4
    const int* srcArr = ei;
    const int* dstArr = ei + E;
    const int nb = (n + 255) / 256;

    // ---- workspace layout ----
    char* w = (char*)d_ws;
    _Float16* xh   = (_Float16*)w;  w += (size_t)MPAD * HIDF * 2;
    _Float16* bufA = (_Float16*)w;  w += (size_t)MPAD * HIDF * 2;
    _Float16* bufB = (_Float16*)w;  w += (size_t)MPAD * HIDF * 2;
    _Float16* whi = (_Float16*)w;  w += (size_t)9 * 65536 * 2;
    _Float16* wlo = (_Float16*)w;  w += (size_t)9 * 65536 * 2;
    _Float16* fahi = (_Float16*)w; w += (size_t)FCM * FCK * 2;
    _Float16* falo = (_Float16*)w; w += (size_t)FCM * FCK * 2;
    _Float16* fwhi = (_Float16*)w; w += (size_t)HIDF * FCK * 2;
    _Float16* fwlo = (_Float16*)w; w += (size_t)HIDF * FCK * 2;
    int2*  esrc   = (int2*)w;   w += (size_t)E * 8;
    int*   offs   = (int*)w;    w += ((size_t)n + 4) * 4;
    int*   cursor = (int*)w;    w += ((size_t)n + 4) * 4;
    int*   cnt    = (int*)w;    w += (size_t)n * 4;
    int*   bsum   = (int*)w;    w += 256 * 4;
    int*   startA = (int*)w;    w += ((size_t)B + 4) * 4;
    float* gacc   = (float*)w;  w += (size_t)MPAD * 4;
    float* pooled = (float*)w;  w += (size_t)B * HIDF * 4;
    float* h      = (float*)w;  w += (size_t)B * HIDF * 4;
    float* mu     = (float*)w;  w += 256 * 4;
    float* rs     = (float*)w;  w += 256 * 4;

    // ---- CSR build (counting sort by dst) + batch starts ----
    hipMemsetAsync(cnt, 0, (size_t)n * 4, stream);
    count_k<<<(E + 255) / 256, 256, 0, stream>>>(dstArr, cnt, E);
    scan1_k<<<nb, 256, 0, stream>>>(cnt, offs, bsum, n);
    scan2_k<<<1, 256, 0, stream>>>(bsum, nb);
    scan3_k<<<nb, 256, 0, stream>>>(offs, bsum, cursor, n, E);
    scatter_k<<<(E + 255) / 256, 256, 0, stream>>>(dstArr, srcArr, ea, cursor, esrc, E);
    start_k<<<(B + 256) / 256, 256, 0, stream>>>(batch, startA, n, B);

    // ---- input fp16 conversion + merged weight split ----
    convxh_k<<<(MPAD * 64 + 255) / 256, 256, 0, stream>>>(x, xh, n);
    dim3 gcw((HIDF * FCK + 255) / 256, 10);
    convw_all_k<<<gcw, 256, 0, stream>>>(lin_w, upd_w, g1w, fc1w, whi, wlo, fwhi, fwlo);
    hipMemsetAsync(gacc, 0, (size_t)MPAD * 4, stream);

    // ---- message passing (both GEMMs 2-term) ----
    dim3 ggm(HIDF / 128, MPAD / 128);
    for (int l = 0; l < L; ++l) {
        const float* we = lin_w + (size_t)l * 257 * 256 + 256 * 256;
        const float* lb = lin_b + (size_t)l * 256;
        gemm_f16<0, 2><<<ggm, 256, 0, stream>>>(xh, whi + (size_t)l * 65536,
                                                wlo + (size_t)l * 65536, lb,
                                                bufA, MPAD, HIDF, HIDF);
        aggregate_k<<<(n * 64 + 255) / 256, 256, 0, stream>>>(
            bufA, we, esrc, offs, bufB, n);
        gemm_f16<1, 2><<<ggm, 256, 0, stream>>>(bufB, whi + (size_t)(4 + l) * 65536,
                                                wlo + (size_t)(4 + l) * 65536,
                                                upd_b + (size_t)l * 256, xh, MPAD, HIDF, HIDF);
    }

    // ---- gating (fused dot, 1-term) + pooling (fused sigmoid) ----
    gemm_gate<<<ggm, 256, 0, stream>>>(xh, whi + (size_t)8 * 65536,
                                       g1b, g2w, gacc, MPAD, HIDF, HIDF);
    pool_k<<<(B * 64 + 255) / 256, 256, 0, stream>>>(xh, gacc, g2b, startA, pooled, B);

    // ---- head: fc1 split-K MFMA (atomic fp32 into zeroed h), BN, final ----
    convfc1a_k<<<(FCM * FCK + 255) / 256, 256, 0, stream>>>(pooled, fp, fahi, falo, B);
    hipMemsetAsync(h, 0, (size_t)B * HIDF * 4, stream);
    dim3 ggf(HIDF / 128, FCM / 128, FCSLICES);
    gemm_fc1<<<ggf, 256, 0, stream>>>(fahi, falo, fwhi, fwlo, h, B, HIDF, FCK);
    bnstats_k<<<256, 256, 0, stream>>>(h, fc1b, mu, rs, B);
    final_k<<<B, 256, 0, stream>>>(h, fc1b, mu, rs, gamma, beta, fc2w, fc2b, out, B);
}